// Round 6
// baseline (779.457 us; speedup 1.0000x reference)
//
#include <hip/hip_runtime.h>
#include <cstddef>

#define Hdim 1024
#define Bdim 64
#define Idim 128

// BETA = 10.0 / 0.192
#define BETA_F 52.083333333333336f
#define INV_BETA_F 0.0192f
#define LN2_F 0.6931471805599453f

__device__ __forceinline__ float sigf(float x) {
    return 1.0f / (1.0f + __expf(-x));
}

// fast sigmoid: v_exp + v_rcp (1-ulp rcp; absmax budget is 5.5e-3, ~50x slack)
__device__ __forceinline__ float sigf_fast(float x) {
    return __builtin_amdgcn_rcpf(1.0f + __expf(-x));
}

// log(cosh(t)) = |t| + log(1+exp(-2|t|)) - ln2 ; |t| <= ~1.63 here so the
// argument of log is in [1.04, 2] — v_log_f32 precision is fine.
__device__ __forceinline__ float logcoshf_fast(float t) {
    float a = fabsf(t);
    return a + __logf(1.0f + __expf(-2.0f * a)) - LN2_F;
}

// ---------------------------------------------------------------------------
// Pre-kernel: rates r = sigmoid(v_t)  (flat B*H),
// and x-projections: membx[j,b] = p_r@x + b_r ; gatex[j,b] = |p_r|@x + g_z
// grid = H blocks of B threads.
// ---------------------------------------------------------------------------
__global__ void pre_kernel(const float* __restrict__ x,
                           const float* __restrict__ v_t,
                           const float* __restrict__ p_r,
                           const float* __restrict__ b_r,
                           const float* __restrict__ g_z,
                           float* __restrict__ r_ws,
                           float* __restrict__ membx,
                           float* __restrict__ gatex) {
    const int j = blockIdx.x;   // 0..H-1
    const int b = threadIdx.x;  // 0..B-1
    const float* pr = p_r + (size_t)j * Idim;
    float accm = 0.0f, accg = 0.0f;
#pragma unroll 4
    for (int i = 0; i < Idim; ++i) {
        float p  = pr[i];              // wave-uniform -> scalar load
        float xv = x[i * Bdim + b];    // coalesced
        accm = fmaf(p, xv, accm);
        accg = fmaf(fabsf(p), xv, accg);
    }
    membx[j * Bdim + b] = accm + b_r[j];
    gatex[j * Bdim + b] = accg + g_z[j];

    int id = j * Bdim + b;  // flat elementwise over B*H
    r_ws[id] = sigf(v_t[id]);
}

// ---------------------------------------------------------------------------
// Main kernel: grid (4, 1024). Block = one j-row x 16 batches.
//  - Param transforms computed ONCE per block into LDS (redundancy 4x across
//    the 4 batch-groups, vs 32x in R5 which was VALU-bound at 97%), using
//    cheap math (v_exp/v_log/v_rcp) — ~10 us chip-wide.
//  - Single __syncthreads, then barrier-free R3-style streaming: each of the
//    4 waves owns 2 batch-pairs; per chunk 6 independent float4 HBM/L2 loads.
//  - No d_ws param buffers: HBM traffic stays at the ~335 MB floor (R5).
//  - __launch_bounds__(256,8): VGPR<=64, LDS 16 KB -> 8 blocks/CU = 32
//    waves/CU (R3's 87% occupancy regime, which gave 3.2 TB/s).
// ---------------------------------------------------------------------------
__global__ __launch_bounds__(256, 8) void main_kernel(
    const float* __restrict__ X,
    const float* __restrict__ U,
    const float* __restrict__ raw_w_r,
    const float* __restrict__ c_x,
    const float* __restrict__ c_u,
    const float* __restrict__ c_U,
    const float* __restrict__ v_t,
    const float* __restrict__ a_exc,
    const float* __restrict__ a_inh,
    const float* __restrict__ r_ws,
    const float* __restrict__ membx,
    const float* __restrict__ gatex,
    float* __restrict__ out) {
    __shared__ __align__(16) float s_zx[Hdim];
    __shared__ __align__(16) float s_zu[Hdim];
    __shared__ __align__(16) float s_uc[Hdim];
    __shared__ __align__(16) float s_wr[Hdim];

    const int j   = blockIdx.y;
    const int tid = threadIdx.x;

    // ---- stage per-row transforms into LDS (256 thr x 4 elems, fast math) --
    {
        const int k = tid * 4;
        const size_t ro = (size_t)j * Hdim + k;
        float4 rw = *(const float4*)(raw_w_r + ro);
        float4 cx = *(const float4*)(c_x + ro);
        float4 cu = *(const float4*)(c_u + ro);
        float4 cN = *(const float4*)(c_U + ro);

        s_wr[k + 0] = logcoshf_fast(BETA_F * rw.x) * INV_BETA_F;
        s_wr[k + 1] = logcoshf_fast(BETA_F * rw.y) * INV_BETA_F;
        s_wr[k + 2] = logcoshf_fast(BETA_F * rw.z) * INV_BETA_F;
        s_wr[k + 3] = logcoshf_fast(BETA_F * rw.w) * INV_BETA_F;

        s_zx[k + 0] = 0.001f + 0.099f * sigf_fast(cx.x);
        s_zx[k + 1] = 0.001f + 0.099f * sigf_fast(cx.y);
        s_zx[k + 2] = 0.001f + 0.099f * sigf_fast(cx.z);
        s_zx[k + 3] = 0.001f + 0.099f * sigf_fast(cx.w);

        s_zu[k + 0] = 0.001f + 0.099f * sigf_fast(cu.x);
        s_zu[k + 1] = 0.001f + 0.099f * sigf_fast(cu.y);
        s_zu[k + 2] = 0.001f + 0.099f * sigf_fast(cu.z);
        s_zu[k + 3] = 0.001f + 0.099f * sigf_fast(cu.w);

        s_uc[k + 0] = 0.9f * sigf_fast(cN.x);
        s_uc[k + 1] = 0.9f * sigf_fast(cN.y);
        s_uc[k + 2] = 0.9f * sigf_fast(cN.z);
        s_uc[k + 3] = 0.9f * sigf_fast(cN.w);
    }
    __syncthreads();

    const int wave  = tid >> 6;
    const int lane  = tid & 63;
    const int bbase = blockIdx.x * 16 + wave * 4;  // this wave's 4 batches

    const float Aexc = 10.0f * sigf(a_exc[0]);
    const float Ainh = 10.0f * sigf(a_inh[0]);

    for (int pair = 0; pair < 2; ++pair) {
        const int b0 = bbase + 2 * pair;
        const float* X0 = X + ((size_t)b0 * Hdim + j) * Hdim;
        const float* X1 = X0 + (size_t)Hdim * Hdim;
        const float* U0 = U + ((size_t)b0 * Hdim + j) * Hdim;
        const float* U1 = U0 + (size_t)Hdim * Hdim;
        const float* rr0 = r_ws + b0 * Hdim;
        const float* rr1 = rr0 + Hdim;

        const float rj0 = rr0[j];
        const float rj1 = rr1[j];

        float rec0 = 0.f, rec1 = 0.f;
        float ge0 = 0.f, ge1 = 0.f;   // gate partial, k < 512 (excitatory)
        float gi0 = 0.f, gi1 = 0.f;   // gate partial, k >= 512 (inhibitory)

#pragma unroll
        for (int chunk = 0; chunk < 4; ++chunk) {
            const int k = chunk * 256 + lane * 4;
            float4 Xv0 = *(const float4*)(X0 + k);
            float4 Uv0 = *(const float4*)(U0 + k);
            float4 Xv1 = *(const float4*)(X1 + k);
            float4 Uv1 = *(const float4*)(U1 + k);
            float4 r0  = *(const float4*)(rr0 + k);
            float4 r1  = *(const float4*)(rr1 + k);
            float4 zx  = *(const float4*)(s_zx + k);
            float4 zu  = *(const float4*)(s_zu + k);
            float4 uc  = *(const float4*)(s_uc + k);
            float4 wr  = *(const float4*)(s_wr + k);

            float g0 = 0.f, g1 = 0.f;
#define COMPONENT(c)                                                          \
    {                                                                         \
        float xn0 = zx.c + (1.0f - zx.c) * Xv0.c - Uv0.c * Xv0.c * rj0;       \
        float un0 = uc.c * zu.c + (1.0f - zu.c) * Uv0.c +                     \
                    uc.c * (1.0f - Uv0.c) * rj0;                              \
        un0 = fminf(fmaxf(un0, uc.c), 1.0f);                                  \
        rec0 = fmaf(xn0 * un0 * wr.c, r0.c, rec0);                            \
        g0   = fmaf(wr.c, r0.c, g0);                                          \
        float xn1 = zx.c + (1.0f - zx.c) * Xv1.c - Uv1.c * Xv1.c * rj1;       \
        float un1 = uc.c * zu.c + (1.0f - zu.c) * Uv1.c +                     \
                    uc.c * (1.0f - Uv1.c) * rj1;                              \
        un1 = fminf(fmaxf(un1, uc.c), 1.0f);                                  \
        rec1 = fmaf(xn1 * un1 * wr.c, r1.c, rec1);                            \
        g1   = fmaf(wr.c, r1.c, g1);                                          \
    }
            COMPONENT(x)
            COMPONENT(y)
            COMPONENT(z)
            COMPONENT(w)
#undef COMPONENT
            if (chunk < 2) { ge0 += g0; ge1 += g1; }
            else           { gi0 += g0; gi1 += g1; }
        }

        float gate0 = fmaf(Aexc, ge0, Ainh * gi0);
        float gate1 = fmaf(Aexc, ge1, Ainh * gi1);

#pragma unroll
        for (int off = 32; off > 0; off >>= 1) {
            rec0  += __shfl_xor(rec0, off, 64);
            rec1  += __shfl_xor(rec1, off, 64);
            gate0 += __shfl_xor(gate0, off, 64);
            gate1 += __shfl_xor(gate1, off, 64);
        }

        if (lane == 0) {
            {
                float z  = 0.1f * sigf(gate0 + gatex[j * Bdim + b0]);
                float vt = v_t[(size_t)b0 * Hdim + j];
                out[(size_t)b0 * Hdim + j] =
                    (1.0f - z) * vt + 0.1f * (rec0 + membx[j * Bdim + b0]);
            }
            {
                const int b = b0 + 1;
                float z  = 0.1f * sigf(gate1 + gatex[j * Bdim + b]);
                float vt = v_t[(size_t)b * Hdim + j];
                out[(size_t)b * Hdim + j] =
                    (1.0f - z) * vt + 0.1f * (rec1 + membx[j * Bdim + b]);
            }
        }
    }
}

extern "C" void kernel_launch(void* const* d_in, const int* in_sizes, int n_in,
                              void* d_out, int out_size, void* d_ws, size_t ws_size,
                              hipStream_t stream) {
    const float* x       = (const float*)d_in[0];   // (I,B)
    const float* v_t     = (const float*)d_in[1];   // (B,H)
    const float* X       = (const float*)d_in[2];   // (B,H,H)
    const float* U       = (const float*)d_in[3];   // (B,H,H)
    const float* raw_w_r = (const float*)d_in[4];   // (H,H)
    const float* p_r     = (const float*)d_in[5];   // (H,I)
    const float* b_r     = (const float*)d_in[6];   // (H,1)
    const float* g_z     = (const float*)d_in[7];   // (H,1)
    const float* c_x     = (const float*)d_in[8];   // (H,H)
    const float* c_u     = (const float*)d_in[9];   // (H,H)
    const float* c_U     = (const float*)d_in[10];  // (H,H)
    const float* a_exc   = (const float*)d_in[11];  // scalar
    const float* a_inh   = (const float*)d_in[12];  // scalar

    float* out = (float*)d_out;  // (B,H) fp32

    float* r_ws  = (float*)d_ws;              // B*H
    float* membx = r_ws + Bdim * Hdim;        // H*B
    float* gatex = membx + Hdim * Bdim;       // H*B

    pre_kernel<<<dim3(Hdim), dim3(Bdim), 0, stream>>>(
        x, v_t, p_r, b_r, g_z, r_ws, membx, gatex);

    main_kernel<<<dim3(4, Hdim), dim3(256), 0, stream>>>(
        X, U, raw_w_r, c_x, c_u, c_U, v_t, a_exc, a_inh,
        r_ws, membx, gatex, out);
}